// Round 9
// baseline (304.649 us; speedup 1.0000x reference)
//
#include <hip/hip_runtime.h>

#define IN_SIZE 256
#define N_NODES 1024
#define DEG 32
#define BATCH 16384
#define OUT_SIZE 16
#define COLS 8                        // batch columns per single-wave block
#define N_ROWS (IN_SIZE + N_NODES)    // 1280 activation rows (fp32 in LDS)
#define NPAIR (N_NODES / 2)           // 512 node pairs

// RNE float -> bf16
__device__ __forceinline__ unsigned short f2bf_rne(float f) {
    const unsigned u = __float_as_uint(f);
    return (unsigned short)((u + 0x7FFFu + ((u >> 16) & 1u)) >> 16);
}

// overflow-free tanh: s = e^{-2|z|}, t = sign(z)*(1-s)/(1+s)
__device__ __forceinline__ float tanh6(float z) {
    const float s = __expf(-2.0f * fabsf(z));
    const float r = __builtin_amdgcn_rcpf(1.0f + s);
    return copysignf(fmaf(-s, r, r), z);
}

// butterfly add across lane bits {0,1,2} within 8-aligned groups:
// quad_perm(B1)=xor1, quad_perm(4E)=xor2, row_half_mirror(0x141)=mirror-in-8
// (== xor4 once quads are uniform). Full 8-lane sum in every lane. HW-proven.
template <int CTRL>
__device__ __forceinline__ float dpp_add(float v) {
    return v + __int_as_float(__builtin_amdgcn_mov_dpp(__float_as_int(v), CTRL, 0xF, 0xF, true));
}

// ---------------------------------------------------------------------------
// Runtime dtype detector (unchanged).
// ---------------------------------------------------------------------------
__global__ __launch_bounds__(64) void ne_detect(const void* __restrict__ xraw,
                                                int* __restrict__ flag) {
    const unsigned short* xb = (const unsigned short*)xraw;
    const int tid = threadIdx.x;
    int plausible = 0;
    for (int k = tid; k < 2048; k += 64) {
        const float v = __uint_as_float((unsigned)xb[2 * k] << 16);
        const float a = fabsf(v);
        plausible += (a == 0.0f) || (a > 1e-3f && a < 1e3f) ? 1 : 0;
    }
    for (int off = 32; off > 0; off >>= 1) plausible += __shfl_down(plausible, off);
    if (tid == 0) *flag = (plausible >= (2048 * 9) / 10) ? 1 : 0;
}

// ---------------------------------------------------------------------------
// Packed tables for the pair structure, per lane q = 0..7:
//   pki[P*16 + q*2 + e] = int4  ids[2P+e][4q..4q+3]   (e = node parity)
//   pkw[P*16 + q*2 + e] = float4 w [2P+e][4q..4q+3]
//   hze4[P*8+q] = {h1,h2,h3,h4} of even node 2P   (replicated over q)
//   hzo4[P*8+q] = {h2,h3,h4,h5} of odd  node 2P+1
//   h1o [P*8+q] = h1 of odd node (in-pair coeff)
// where h_k(n) = sum_r w[n][r]*[idx[n][r]==256+n-k] (idx>=256 only).
// Prefolds in forward dot BOTH coeff vectors with {to1,te1,to2,te2}.
// All hot-loop loads are per-lane vector loads (vmcnt-only; no s_load poison).
// ---------------------------------------------------------------------------
__global__ __launch_bounds__(256) void ne_prep(const void* __restrict__ wraw,
                                               const int* __restrict__ idxs,
                                               int4* __restrict__ pki,
                                               float4* __restrict__ pkw,
                                               float4* __restrict__ hze4,
                                               float4* __restrict__ hzo4,
                                               float* __restrict__ h1o,
                                               const int* __restrict__ flag) {
    const int isbf16 = *flag;                    // uniform
    const int tid = blockIdx.x * 256 + threadIdx.x;
    const int stride = gridDim.x * 256;
    const unsigned short* wb = (const unsigned short*)wraw;
    const float* wsrc = (const float*)wraw;
    for (int k = tid; k < N_NODES * 8; k += stride) {   // k = n*8 + qq
        const int n = k >> 3, qq = k & 7;
        const int e = n * DEG + qq * 4;
        const int dest = (n >> 1) * 16 + qq * 2 + (n & 1);
        pki[dest] = make_int4(idxs[e], idxs[e + 1], idxs[e + 2], idxs[e + 3]);
        float w0 = isbf16 ? __uint_as_float((unsigned)wb[e + 0] << 16) : wsrc[e + 0];
        float w1 = isbf16 ? __uint_as_float((unsigned)wb[e + 1] << 16) : wsrc[e + 1];
        float w2 = isbf16 ? __uint_as_float((unsigned)wb[e + 2] << 16) : wsrc[e + 2];
        float w3 = isbf16 ? __uint_as_float((unsigned)wb[e + 3] << 16) : wsrc[e + 3];
        pkw[dest] = make_float4(w0, w1, w2, w3);
    }
    for (int n = tid; n < N_NODES; n += stride) {
        float h1 = 0.f, h2 = 0.f, h3 = 0.f, h4 = 0.f, h5 = 0.f;
        for (int r = 0; r < DEG; ++r) {
            const int id = idxs[n * DEG + r];
            if (id < IN_SIZE) continue;          // input rows are never stale
            const int d = IN_SIZE + n - id;      // id == 256+n-d
            if (d < 1 || d > 5) continue;
            const float w = isbf16 ? __uint_as_float((unsigned)wb[n * DEG + r] << 16)
                                   : wsrc[n * DEG + r];
            if (d == 1) h1 += w; else if (d == 2) h2 += w; else if (d == 3) h3 += w;
            else if (d == 4) h4 += w; else h5 += w;
        }
        const int P = n >> 1;
        if ((n & 1) == 0) {
#pragma unroll
            for (int r = 0; r < 8; ++r) hze4[P * 8 + r] = make_float4(h1, h2, h3, h4);
        } else {
#pragma unroll
            for (int r = 0; r < 8; ++r) {
                hzo4[P * 8 + r] = make_float4(h2, h3, h4, h5);
                h1o[P * 8 + r] = h1;
            }
        }
    }
}

// ---------------------------------------------------------------------------
// COLS=8 pair pipeline (40 KB LDS -> 4 blocks/CU, 1 wave/SIMD, 2 rounds).
// lane = c*8 + q: q = fan-in quad, c = batch column. Each lane gathers 4
// elems of the EVEN node and 4 of the ODD node; two 3-DPP reduces leave both
// full sums in every lane -> no ror8, no parity packing: prefolds are plain
// FMAs on registers te1,to1,te2,to2. Per step S:
//   1) reduce pair S+1 (8 FMA + 6 DPP; independent of t-chain)
//   2) issue gathers pair S+2 (before write(S): stale pairs S..S+2 read the
//      pre-zeroed 0.0 and are folded back exactly via hze/hzo/h1o)
//   3) finalize pair S: 8 prefold FMA; te=tanh(ze); zo+=h1o*te; to=tanh(zo);
//      lanes q<2 write rows 2S,2S+1
//   4) refills: w(S+3), ids(S+4), hz(S+2) — all per-lane dwordx4/dword
// Single wave => in-order DS => stale reads deterministically 0; no barriers.
// ---------------------------------------------------------------------------
__global__ __launch_bounds__(64) void ne_forward(const void* __restrict__ xraw,
                                                 const int4* __restrict__ pki,
                                                 const float4* __restrict__ pkw,
                                                 const float4* __restrict__ hze4,
                                                 const float4* __restrict__ hzo4,
                                                 const float* __restrict__ h1o,
                                                 void* __restrict__ outraw,
                                                 const int* __restrict__ flag) {
    __shared__ float act[N_ROWS * COLS];         // 40960 B -> 4 blocks/CU
    const int lane = threadIdx.x;
    const int q = lane & 7;                      // fan-in quad 0..7
    const int c = lane >> 3;                     // batch column 0..7
    const int c0 = blockIdx.x * COLS;
    const int q2 = q * 2;
    const int isbf16 = *flag;                    // uniform
    float* outf = (float*)outraw;
    unsigned short* outb = (unsigned short*)outraw;

    // ---- zero node rows so stale gathers read exactly 0.0 ----
    {
        float4* az = (float4*)(act + IN_SIZE * COLS);   // 2048 float4
#pragma unroll
        for (int t = 0; t < 32; ++t) az[t * 64 + lane] = make_float4(0.f, 0.f, 0.f, 0.f);
    }
    // ---- seed input rows 0..255 from raw x (b = column, seg = 32-elem chunk) ----
    {
        const int b = lane >> 3;
        const int seg = lane & 7;
        if (isbf16) {
            const unsigned short* xb =
                (const unsigned short*)xraw + (size_t)(c0 + b) * IN_SIZE + seg * 32;
#pragma unroll
            for (int t = 0; t < 4; ++t) {
                const uint4 v = *(const uint4*)(xb + t * 8);
                const int k0 = seg * 32 + t * 8;
                act[(k0 + 0) * COLS + b] = __uint_as_float(v.x << 16);
                act[(k0 + 1) * COLS + b] = __uint_as_float(v.x & 0xFFFF0000u);
                act[(k0 + 2) * COLS + b] = __uint_as_float(v.y << 16);
                act[(k0 + 3) * COLS + b] = __uint_as_float(v.y & 0xFFFF0000u);
                act[(k0 + 4) * COLS + b] = __uint_as_float(v.z << 16);
                act[(k0 + 5) * COLS + b] = __uint_as_float(v.z & 0xFFFF0000u);
                act[(k0 + 6) * COLS + b] = __uint_as_float(v.w << 16);
                act[(k0 + 7) * COLS + b] = __uint_as_float(v.w & 0xFFFF0000u);
            }
        } else {
            const float* xs = (const float*)xraw + (size_t)(c0 + b) * IN_SIZE + seg * 32;
#pragma unroll
            for (int t = 0; t < 8; ++t) {
                const float4 v = *(const float4*)(xs + t * 4);
                const int k0 = seg * 32 + t * 4;
                act[(k0 + 0) * COLS + b] = v.x;
                act[(k0 + 1) * COLS + b] = v.y;
                act[(k0 + 2) * COLS + b] = v.z;
                act[(k0 + 3) * COLS + b] = v.w;
            }
        }
    }
    // single wave: in-order DS -> gathers below see the seed; no barrier

    // ---- prologue ----
    float zeA, zoA, zeB, zoB;
    float gE0, gE1, gE2, gE3, gO0, gO1, gO2, gO3;
    {   // pair 0: load, gather, reduce immediately (transient)
        const int4 iE = pki[0 * 16 + q2], iO = pki[0 * 16 + q2 + 1];
        const float4 wE = pkw[0 * 16 + q2], wO = pkw[0 * 16 + q2 + 1];
        float ze = act[iE.x * COLS + c] * wE.x;
        ze = fmaf(act[iE.y * COLS + c], wE.y, ze);
        ze = fmaf(act[iE.z * COLS + c], wE.z, ze);
        ze = fmaf(act[iE.w * COLS + c], wE.w, ze);
        float zo = act[iO.x * COLS + c] * wO.x;
        zo = fmaf(act[iO.y * COLS + c], wO.y, zo);
        zo = fmaf(act[iO.z * COLS + c], wO.z, zo);
        zo = fmaf(act[iO.w * COLS + c], wO.w, zo);
        ze = dpp_add<0xB1>(ze); ze = dpp_add<0x4E>(ze); ze = dpp_add<0x141>(ze);
        zo = dpp_add<0xB1>(zo); zo = dpp_add<0x4E>(zo); zo = dpp_add<0x141>(zo);
        zeA = ze; zoA = zo;
    }
    {   // gathers pair 1 (consumed at step 0's reduce)
        const int4 iE = pki[1 * 16 + q2], iO = pki[1 * 16 + q2 + 1];
        gE0 = act[iE.x * COLS + c]; gE1 = act[iE.y * COLS + c];
        gE2 = act[iE.z * COLS + c]; gE3 = act[iE.w * COLS + c];
        gO0 = act[iO.x * COLS + c]; gO1 = act[iO.y * COLS + c];
        gO2 = act[iO.z * COLS + c]; gO3 = act[iO.w * COLS + c];
    }
    // prime streams: slotA {w(1), ids(2), hz(0)}, slotB {w(2), ids(3), hz(1)}
    int4   idE0 = pki[2 * 16 + q2], idO0 = pki[2 * 16 + q2 + 1];
    int4   idE1 = pki[3 * 16 + q2], idO1 = pki[3 * 16 + q2 + 1];
    float4 wvE0 = pkw[1 * 16 + q2], wvO0 = pkw[1 * 16 + q2 + 1];
    float4 wvE1 = pkw[2 * 16 + q2], wvO1 = pkw[2 * 16 + q2 + 1];
    float4 heA = hze4[0 * 8 + q], hoA = hzo4[0 * 8 + q];
    float4 heB = hze4[1 * 8 + q], hoB = hzo4[1 * 8 + q];
    float  c1A = h1o[0 * 8 + q],  c1B = h1o[1 * 8 + q];
    float te1 = 0.f, to1 = 0.f, te2 = 0.f, to2 = 0.f;

#define PAIRSTEP(S, IDE, IDO, WVE, WVO, HZE, HZO, H1, ZEc, ZOc, ZEn, ZOn, OUT, CLAMP)  \
    {                                                                                  \
        /* 1) reduce pair S+1 (independent of t-chain) */                              \
        float ze = gE0 * WVE.x; ze = fmaf(gE1, WVE.y, ze);                             \
        ze = fmaf(gE2, WVE.z, ze); ze = fmaf(gE3, WVE.w, ze);                          \
        float zo = gO0 * WVO.x; zo = fmaf(gO1, WVO.y, zo);                             \
        zo = fmaf(gO2, WVO.z, zo); zo = fmaf(gO3, WVO.w, zo);                          \
        ze = dpp_add<0xB1>(ze); ze = dpp_add<0x4E>(ze); ze = dpp_add<0x141>(ze);       \
        zo = dpp_add<0xB1>(zo); zo = dpp_add<0x4E>(zo); zo = dpp_add<0x141>(zo);       \
        ZEn = ze; ZOn = zo;                                                            \
        /* 2) issue gathers pair S+2 (stale pairs S..S+2 covered exactly) */           \
        gE0 = act[IDE.x * COLS + c]; gE1 = act[IDE.y * COLS + c];                      \
        gE2 = act[IDE.z * COLS + c]; gE3 = act[IDE.w * COLS + c];                      \
        gO0 = act[IDO.x * COLS + c]; gO1 = act[IDO.y * COLS + c];                      \
        gO2 = act[IDO.z * COLS + c]; gO3 = act[IDO.w * COLS + c];                      \
        /* 3) finalize pair S */                                                       \
        float zE = fmaf(HZE.x, to1, ZEc); zE = fmaf(HZE.y, te1, zE);                   \
        zE = fmaf(HZE.z, to2, zE); zE = fmaf(HZE.w, te2, zE);                          \
        float zO = fmaf(HZO.x, to1, ZOc); zO = fmaf(HZO.y, te1, zO);                   \
        zO = fmaf(HZO.z, to2, zO); zO = fmaf(HZO.w, te2, zO);                          \
        const float te = tanh6(zE);                                                    \
        zO = fmaf(H1, te, zO);                                                         \
        const float to = tanh6(zO);                                                    \
        if (q < 2) {                                                                   \
            act[(IN_SIZE + 2 * (S) + q) * COLS + c] = q ? to : te;                     \
            if (OUT) {                                                                 \
                const size_t o =                                                       \
                    (size_t)(2 * (S) + q - (N_NODES - OUT_SIZE)) * BATCH + c0 + c;     \
                if (isbf16) outb[o] = f2bf_rne(q ? to : te);                           \
                else        outf[o] = q ? to : te;                                     \
            }                                                                          \
        }                                                                              \
        te2 = te1; to2 = to1; te1 = te; to1 = to;                                      \
        /* 4) refills: w(S+3), ids(S+4), hz(S+2) */                                    \
        { const int Pw = (CLAMP) ? (((S) + 3 < NPAIR) ? (S) + 3 : NPAIR - 1) : (S) + 3;\
          const int Pn = (CLAMP) ? (((S) + 4 < NPAIR) ? (S) + 4 : NPAIR - 1) : (S) + 4;\
          const int Ph = (CLAMP) ? (((S) + 2 < NPAIR) ? (S) + 2 : NPAIR - 1) : (S) + 2;\
          WVE = pkw[Pw * 16 + q2]; WVO = pkw[Pw * 16 + q2 + 1];                        \
          IDE = pki[Pn * 16 + q2]; IDO = pki[Pn * 16 + q2 + 1];                        \
          HZE = hze4[Ph * 8 + q]; HZO = hzo4[Ph * 8 + q]; H1 = h1o[Ph * 8 + q]; }      \
    }

    // main loop: pairs 0..503 (nodes 0..1007) — no output, no clamp (S+4 <= 507)
#pragma unroll 1
    for (int S = 0; S < NPAIR - 8; S += 2) {
        PAIRSTEP(S,     idE0, idO0, wvE0, wvO0, heA, hoA, c1A, zeA, zoA, zeB, zoB, 0, 0)
        PAIRSTEP(S + 1, idE1, idO1, wvE1, wvO1, heB, hoB, c1B, zeB, zoB, zeA, zoA, 0, 0)
    }
    // epilogue: pairs 504..511 (nodes 1008..1023 — all outputs)
    {
        const int S = NPAIR - 8;                 // 504 (even -> slot parity holds)
        PAIRSTEP(S + 0, idE0, idO0, wvE0, wvO0, heA, hoA, c1A, zeA, zoA, zeB, zoB, 1, 1)
        PAIRSTEP(S + 1, idE1, idO1, wvE1, wvO1, heB, hoB, c1B, zeB, zoB, zeA, zoA, 1, 1)
        PAIRSTEP(S + 2, idE0, idO0, wvE0, wvO0, heA, hoA, c1A, zeA, zoA, zeB, zoB, 1, 1)
        PAIRSTEP(S + 3, idE1, idO1, wvE1, wvO1, heB, hoB, c1B, zeB, zoB, zeA, zoA, 1, 1)
        PAIRSTEP(S + 4, idE0, idO0, wvE0, wvO0, heA, hoA, c1A, zeA, zoA, zeB, zoB, 1, 1)
        PAIRSTEP(S + 5, idE1, idO1, wvE1, wvO1, heB, hoB, c1B, zeB, zoB, zeA, zoA, 1, 1)
        PAIRSTEP(S + 6, idE0, idO0, wvE0, wvO0, heA, hoA, c1A, zeA, zoA, zeB, zoB, 1, 1)
        PAIRSTEP(S + 7, idE1, idO1, wvE1, wvO1, heB, hoB, c1B, zeB, zoB, zeA, zoA, 1, 1)
    }
#undef PAIRSTEP
}

extern "C" void kernel_launch(void* const* d_in, const int* in_sizes, int n_in,
                              void* d_out, int out_size, void* d_ws, size_t ws_size,
                              hipStream_t stream) {
    const void* x   = d_in[0];                   // [BATCH][IN_SIZE]
    const void* w   = d_in[1];                   // [N_NODES][DEG]
    const int* idxs = (const int*)d_in[2];       // [N_NODES][DEG]

    int4*   pki  = (int4*)d_ws;                                          // 128 KB
    float4* pkw  = (float4*)((char*)d_ws + (size_t)128 * 1024);          // 128 KB
    float4* hze4 = (float4*)((char*)d_ws + (size_t)256 * 1024);          // 64 KB
    float4* hzo4 = (float4*)((char*)d_ws + (size_t)320 * 1024);          // 64 KB
    float*  h1o  = (float*)((char*)d_ws + (size_t)384 * 1024);           // 16 KB
    int* flag    = (int*)((char*)d_ws + ((ws_size - 16) & ~(size_t)15));

    ne_detect<<<1, 64, 0, stream>>>(x, flag);
    ne_prep<<<32, 256, 0, stream>>>(w, idxs, pki, pkw, hze4, hzo4, h1o, flag);

    // 2048 single-wave blocks, 40 KB LDS -> 4 blocks/CU (1 wave/SIMD),
    // 2 scheduling rounds, zero barriers.
    ne_forward<<<dim3(BATCH / COLS), dim3(64), 0, stream>>>(x, pki, pkw, hze4, hzo4,
                                                            h1o, d_out, flag);
}